// Round 3
// baseline (202.414 us; speedup 1.0000x reference)
//
#include <hip/hip_runtime.h>
#include <hip/hip_bf16.h>
#include <math.h>

#define B_N 2048
#define T_N 8192
#define NFFT 4096
#define TF_LEN 4097
#define TOPK 5

// padded LDS index for float2 Zs array: breaks power-of-2 stride bank conflicts
#define ZIDX(n) ((n) + ((n) >> 4))
#define ZPAD (NFFT + (NFFT >> 4))  // 4352 float2 slots

typedef float f32x4 __attribute__((ext_vector_type(4)));
typedef __bf16 bf16x8 __attribute__((ext_vector_type(8)));
typedef unsigned short ushort_t;

__device__ __forceinline__ void gload_lds16(const ushort_t* g, ushort_t* l) {
    __builtin_amdgcn_global_load_lds(
        (const __attribute__((address_space(1))) void*)g,
        (__attribute__((address_space(3))) void*)l,
        16, 0, 0);
}

__device__ __forceinline__ float wave_reduce_sum(float v) {
    for (int o = 32; o >= 1; o >>= 1) v += __shfl_xor(v, o, 64);
    return v;
}
__device__ __forceinline__ float wave_reduce_max(float v) {
    for (int o = 32; o >= 1; o >>= 1) v = fmaxf(v, __shfl_xor(v, o, 64));
    return v;
}

__device__ __forceinline__ ushort_t f2bf(float x) {
    __hip_bfloat16 h = __float2bfloat16(x);
    return *reinterpret_cast<ushort_t*>(&h);
}

// native HW trig: input in REVOLUTIONS; cis_rev(r) = (cos(2*pi*r), sin(2*pi*r))
__device__ __forceinline__ float2 cis_rev(float rev) {
    return make_float2(__builtin_amdgcn_cosf(rev), __builtin_amdgcn_sinf(rev));
}
__device__ __forceinline__ float2 cmulf(float2 a, float2 b) {
    return make_float2(a.x * b.x - a.y * b.y, a.x * b.y + a.y * b.x);
}

// ---------------- init ----------------
__global__ void init_kernel(float* acc) {
    if (threadIdx.x < 4) acc[threadIdx.x] = 0.0f;
}

// ---------------- DFT16 in registers (two radix-4 levels) ----------------
__device__ __forceinline__ void dft4(float2 x0, float2 x1, float2 x2, float2 x3,
                                     float2* y0, float2* y1, float2* y2, float2* y3) {
    float2 t0 = make_float2(x0.x + x2.x, x0.y + x2.y);
    float2 t1 = make_float2(x0.x - x2.x, x0.y - x2.y);
    float2 t2 = make_float2(x1.x + x3.x, x1.y + x3.y);
    float2 t3 = make_float2(x1.x - x3.x, x1.y - x3.y);
    *y0 = make_float2(t0.x + t2.x, t0.y + t2.y);
    *y2 = make_float2(t0.x - t2.x, t0.y - t2.y);
    *y1 = make_float2(t1.x + t3.y, t1.y - t3.x);   // t1 + (-i)*t3
    *y3 = make_float2(t1.x - t3.y, t1.y + t3.x);   // t1 - (-i)*t3
}

__device__ __forceinline__ void dft16(float2 X[16]) {
    float2 G[16];
    // G[b*4+c] = DFT4 over a of X[4a+b]
    dft4(X[0], X[4], X[8],  X[12], &G[0],  &G[1],  &G[2],  &G[3]);
    dft4(X[1], X[5], X[9],  X[13], &G[4],  &G[5],  &G[6],  &G[7]);
    dft4(X[2], X[6], X[10], X[14], &G[8],  &G[9],  &G[10], &G[11]);
    dft4(X[3], X[7], X[11], X[15], &G[12], &G[13], &G[14], &G[15]);
    const float C1 = 0.9238795325112867f, S1 = 0.3826834323650898f;
    const float R2 = 0.7071067811865476f;
    // H[b][c] = G[b][c] * W16^{bc}
    G[5]  = cmulf(G[5],  make_float2(C1, -S1));   // W^1
    G[6]  = cmulf(G[6],  make_float2(R2, -R2));   // W^2
    G[7]  = cmulf(G[7],  make_float2(S1, -C1));   // W^3
    G[9]  = cmulf(G[9],  make_float2(R2, -R2));   // W^2
    { float2 g = G[10]; G[10] = make_float2(g.y, -g.x); }  // W^4 = -i
    G[11] = cmulf(G[11], make_float2(-R2, -R2));  // W^6
    G[13] = cmulf(G[13], make_float2(S1, -C1));   // W^3
    G[14] = cmulf(G[14], make_float2(-R2, -R2));  // W^6
    G[15] = cmulf(G[15], make_float2(-C1, S1));   // W^9
    // Y[c+4d] = DFT4 over b of H[b][c]
    dft4(G[0], G[4], G[8],  G[12], &X[0], &X[4], &X[8],  &X[12]);
    dft4(G[1], G[5], G[9],  G[13], &X[1], &X[5], &X[9],  &X[13]);
    dft4(G[2], G[6], G[10], G[14], &X[2], &X[6], &X[10], &X[14]);
    dft4(G[3], G[7], G[11], G[15], &X[3], &X[7], &X[11], &X[15]);
}

// rfft bin from packed-complex spectrum (exact path, used for top bins)
__device__ __forceinline__ void rfft_bin(const float2* Zs, int k, float* orr, float* oi) {
    int kk = k & (NFFT - 1);
    int nk = (NFFT - k) & (NFFT - 1);
    float2 zk = Zs[ZIDX(kk)], znk = Zs[ZIDX(nk)];
    float xer = 0.5f * (zk.x + znk.x);
    float xei = 0.5f * (zk.y - znk.y);
    float xo_r = 0.5f * (zk.y + znk.y);
    float xo_i = -0.5f * (zk.x - znk.x);
    float2 w = cis_rev((float)k * (-1.0f / (float)T_N));
    *orr = xer + w.x * xo_r - w.y * xo_i;
    *oi = xei + w.x * xo_i + w.y * xo_r;
}

// ---------------- fused per-row kernel: prep + ashift + phase ----------------
__global__ __launch_bounds__(256) void fused_row_kernel(const float* __restrict__ inp,
                                                        const float* __restrict__ tgt,
                                                        ushort_t* __restrict__ Abf,
                                                        ushort_t* __restrict__ Bbf,
                                                        float* acc) {
    __shared__ float2 Zs[ZPAD];
    __shared__ __align__(16) float amp[TF_LEN];
    __shared__ float red[4];
    __shared__ float wv[4];
    __shared__ int wi[4];
    __shared__ int topIdx[TOPK];
    __shared__ float2 tgtF[TOPK];
    __shared__ float rscratch[64];

    int b = blockIdx.x;
    int tid = threadIdx.x;
    int lane = tid & 63, wid = tid >> 6;
    const float* tp = tgt + (size_t)b * T_N;
    const float* ip = inp + (size_t)b * T_N;
    ushort_t* Ab = Abf + (size_t)b * T_N;
    ushort_t* Bb = Bbf + (size_t)b * T_N;

    // ---- load tgt: regs + Abf + digit-reversed complex scatter into Zs ----
    float4 trv[8];
#pragma unroll
    for (int i = 0; i < 8; i++) {
        int q = tid + 256 * i;
        trv[i] = *reinterpret_cast<const float4*>(&tp[4 * q]);
        ushort4 ua;
        ua.x = f2bf(trv[i].x); ua.y = f2bf(trv[i].y);
        ua.z = f2bf(trv[i].z); ua.w = f2bf(trv[i].w);
        *reinterpret_cast<ushort4*>(&Ab[4 * q]) = ua;
        int m0 = 2 * q, m1 = 2 * q + 1;
        int p0 = ((m0 & 15) << 8) | (m0 & 0x0F0) | (m0 >> 8);
        int p1 = ((m1 & 15) << 8) | (m1 & 0x0F0) | (m1 >> 8);
        Zs[ZIDX(p0)] = make_float2(trv[i].x, trv[i].y);
        Zs[ZIDX(p1)] = make_float2(trv[i].z, trv[i].w);
    }

    // ---- load inp; d = inp - tgt (tgt regs die here) ----
    float4 irv[8], dv[8];
#pragma unroll
    for (int i = 0; i < 8; i++) {
        int q = tid + 256 * i;
        irv[i] = *reinterpret_cast<const float4*>(&ip[4 * q]);
        dv[i] = make_float4(irv[i].x - trv[i].x, irv[i].y - trv[i].y,
                            irv[i].z - trv[i].z, irv[i].w - trv[i].w);
    }

    // ---- Bbf = bf16(-d reversed), via two 16KB pings through amp[] ----
    float* ampf = amp;
#pragma unroll
    for (int i = 0; i < 4; i++)  // d[0..4095] -> ampf quads [0,1024)
        *reinterpret_cast<float4*>(&ampf[4 * (tid + 256 * i)]) = dv[i];
    __syncthreads();
#pragma unroll
    for (int i2 = 0; i2 < 4; i2++) {  // Bbf quads [1024,2048)
        int qr = 1024 + tid + 256 * i2;
        float4 v = *reinterpret_cast<const float4*>(&ampf[4 * (1023 - tid - 256 * i2)]);
        ushort4 ub;
        ub.x = f2bf(-v.w); ub.y = f2bf(-v.z); ub.z = f2bf(-v.y); ub.w = f2bf(-v.x);
        *reinterpret_cast<ushort4*>(&Bb[4 * qr]) = ub;
    }
    __syncthreads();
#pragma unroll
    for (int i = 4; i < 8; i++)  // d[4096..8191] -> ampf quads [0,1024)
        *reinterpret_cast<float4*>(&ampf[4 * (tid + 256 * (i - 4))]) = dv[i];
    __syncthreads();
#pragma unroll
    for (int i2 = 0; i2 < 4; i2++) {  // Bbf quads [0,1024)
        int qr = tid + 256 * i2;
        float4 v = *reinterpret_cast<const float4*>(&ampf[4 * (1023 - tid - 256 * i2)]);
        ushort4 ub;
        ub.x = f2bf(-v.w); ub.y = f2bf(-v.z); ub.z = f2bf(-v.y); ub.w = f2bf(-v.x);
        *reinterpret_cast<ushort4*>(&Bb[4 * qr]) = ub;
    }
    __syncthreads();

    // ---- ashift from d registers ----
    {
        float lmax = -1e30f;
#pragma unroll
        for (int i = 0; i < 8; i++)
            lmax = fmaxf(lmax, fmaxf(fmaxf(dv[i].x, dv[i].y), fmaxf(dv[i].z, dv[i].w)));
        lmax = wave_reduce_max(lmax);
        if (lane == 0) red[wid] = lmax;
        __syncthreads();
        float mx = fmaxf(fmaxf(red[0], red[1]), fmaxf(red[2], red[3]));
        __syncthreads();
        float lsum = 0.0f;
#pragma unroll
        for (int i = 0; i < 8; i++) {
            dv[i].x = __expf(dv[i].x - mx);
            dv[i].y = __expf(dv[i].y - mx);
            dv[i].z = __expf(dv[i].z - mx);
            dv[i].w = __expf(dv[i].w - mx);
            lsum += (dv[i].x + dv[i].y) + (dv[i].z + dv[i].w);
        }
        lsum = wave_reduce_sum(lsum);
        if (lane == 0) red[wid] = lsum;
        __syncthreads();
        float Z = (red[0] + red[1]) + (red[2] + red[3]);
        __syncthreads();
        float inv = 1.0f / Z;
        const float u = 1.0f / (float)T_N;
        float labs = 0.0f;
#pragma unroll
        for (int i = 0; i < 8; i++) {
            labs += fabsf(u - dv[i].x * inv) + fabsf(u - dv[i].y * inv) +
                    fabsf(u - dv[i].z * inv) + fabsf(u - dv[i].w * inv);
        }
        labs = wave_reduce_sum(labs);
        if (lane == 0) red[wid] = labs;
        __syncthreads();
        if (tid == 0)
            atomicAdd(acc + 0, (red[0] + red[1]) + (red[2] + red[3]));
    }
    __syncthreads();

    // ---- FFT: 3 radix-16 passes, in place (digit-reversed input) ----
    {  // pass 0: base 16t, stride 1, no twiddle
        float2 X[16];
        int base = tid * 16;
#pragma unroll
        for (int r = 0; r < 16; r++) X[r] = Zs[ZIDX(base + r)];
        dft16(X);
#pragma unroll
        for (int r = 0; r < 16; r++) Zs[ZIDX(base + r)] = X[r];
    }
    __syncthreads();
    {  // pass 1: base = (t>>4)*256 + (t&15), stride 16, twiddle W_256^{j r}
        float2 X[16];
        int j = tid & 15;
        int base = (tid >> 4) * 256 + j;
#pragma unroll
        for (int r = 0; r < 16; r++) X[r] = Zs[ZIDX(base + 16 * r)];
        float2 w1 = cis_rev(-(float)j * (1.0f / 256.0f));
        float2 w = w1;
#pragma unroll
        for (int r = 1; r < 16; r++) { X[r] = cmulf(X[r], w); w = cmulf(w, w1); }
        dft16(X);
#pragma unroll
        for (int r = 0; r < 16; r++) Zs[ZIDX(base + 16 * r)] = X[r];
    }
    __syncthreads();
    {  // pass 2: base = t, stride 256, twiddle W_4096^{t r}
        float2 X[16];
#pragma unroll
        for (int r = 0; r < 16; r++) X[r] = Zs[ZIDX(tid + 256 * r)];
        float2 w1 = cis_rev(-(float)tid * (1.0f / 4096.0f));
        float2 w = w1;
#pragma unroll
        for (int r = 1; r < 16; r++) { X[r] = cmulf(X[r], w); w = cmulf(w, w1); }
        dft16(X);
#pragma unroll
        for (int r = 0; r < 16; r++) Zs[ZIDX(tid + 256 * r)] = X[r];
    }
    __syncthreads();

    // ---- amplitude^2 of rfft bins (rotation recurrence, no sqrt) ----
    {
        float2 rot = cis_rev(-(float)tid * (1.0f / (float)T_N));
        const float2 drot = make_float2(0.9807852804032304f, -0.19509032201612825f);
#pragma unroll
        for (int i = 0; i < 16; i++) {
            int k = tid + 256 * i;
            if (k == 0) {
                amp[0] = -1.0f;
            } else {
                int nk = (NFFT - k) & (NFFT - 1);
                float2 zk = Zs[ZIDX(k & (NFFT - 1))], znk = Zs[ZIDX(nk)];
                float xer = 0.5f * (zk.x + znk.x);
                float xei = 0.5f * (zk.y - znk.y);
                float xo_r = 0.5f * (zk.y + znk.y);
                float xo_i = -0.5f * (zk.x - znk.x);
                float xr = xer + rot.x * xo_r - rot.y * xo_i;
                float xi = xei + rot.x * xo_i + rot.y * xo_r;
                amp[k] = xr * xr + xi * xi;
            }
            rot = cmulf(rot, drot);
        }
        if (tid == 0) {  // Nyquist bin 4096
            float2 z0 = Zs[ZIDX(0)];
            float v = z0.x - z0.y;
            amp[4096] = v * v;
        }
    }
    __syncthreads();

    // ---- top-5 by 5 sequential argmax rounds (tie -> smaller index) ----
    for (int r = 0; r < TOPK; r++) {
        float bv = -3.0f;
        int bi = TF_LEN;
        for (int k = tid; k < TF_LEN; k += 256) {
            float a = amp[k];
            if (a > bv) { bv = a; bi = k; }
        }
        for (int o = 1; o < 64; o <<= 1) {
            float ov = __shfl_xor(bv, o, 64);
            int oi = __shfl_xor(bi, o, 64);
            if (ov > bv || (ov == bv && oi < bi)) { bv = ov; bi = oi; }
        }
        if (lane == 0) { wv[wid] = bv; wi[wid] = bi; }
        __syncthreads();
        if (tid == 0) {
            float fv = wv[0];
            int fi = wi[0];
            for (int w = 1; w < 4; w++)
                if (wv[w] > fv || (wv[w] == fv && wi[w] < fi)) { fv = wv[w]; fi = wi[w]; }
            topIdx[r] = fi;
            amp[fi] = -2.0f;
        }
        __syncthreads();
    }

    // ---- exact target spectrum at top bins ----
    if (tid < TOPK) {
        float xr, xi;
        rfft_bin(Zs, topIdx[tid], &xr, &xi);
        tgtF[tid] = make_float2(xr, xi);
    }
    __syncthreads();

    int fq[TOPK];
#pragma unroll
    for (int q = 0; q < TOPK; q++) fq[q] = topIdx[q];

    // ---- direct DFT of input (from registers) at 5 bins + energy terms ----
    // element t = 4*tid + 1024*i + c; rotor advances by W^f per c (3x) then
    // by wf = W^{f*1021} to jump t -> t+1024 (since 3*1 + 1021 = 1024).
    float2 cur[TOPK], wc[TOPK], wf[TOPK];
    float re[TOPK], im[TOPK];
#pragma unroll
    for (int q = 0; q < TOPK; q++) {
        int f = fq[q];
        cur[q] = cis_rev(-(float)((f * 4 * tid) & (T_N - 1)) * (1.0f / (float)T_N));
        wc[q] = cis_rev(-(float)f * (1.0f / (float)T_N));
        wf[q] = cis_rev(-(float)((f * 1021) & (T_N - 1)) * (1.0f / (float)T_N));
        re[q] = 0.0f; im[q] = 0.0f;
    }
    float E = 0.0f, sev = 0.0f, sod = 0.0f;
#pragma unroll
    for (int i = 0; i < 8; i++) {
        float vv0 = irv[i].x, vv1 = irv[i].y, vv2 = irv[i].z, vv3 = irv[i].w;
        E = fmaf(vv0, vv0, E); sev += vv0;
#pragma unroll
        for (int q = 0; q < TOPK; q++) {
            re[q] = fmaf(vv0, cur[q].x, re[q]); im[q] = fmaf(vv0, cur[q].y, im[q]);
            cur[q] = cmulf(cur[q], wc[q]);
        }
        E = fmaf(vv1, vv1, E); sod += vv1;
#pragma unroll
        for (int q = 0; q < TOPK; q++) {
            re[q] = fmaf(vv1, cur[q].x, re[q]); im[q] = fmaf(vv1, cur[q].y, im[q]);
            cur[q] = cmulf(cur[q], wc[q]);
        }
        E = fmaf(vv2, vv2, E); sev += vv2;
#pragma unroll
        for (int q = 0; q < TOPK; q++) {
            re[q] = fmaf(vv2, cur[q].x, re[q]); im[q] = fmaf(vv2, cur[q].y, im[q]);
            cur[q] = cmulf(cur[q], wc[q]);
        }
        E = fmaf(vv3, vv3, E); sod += vv3;
#pragma unroll
        for (int q = 0; q < TOPK; q++) {
            re[q] = fmaf(vv3, cur[q].x, re[q]); im[q] = fmaf(vv3, cur[q].y, im[q]);
            cur[q] = cmulf(cur[q], wf[q]);  // jump to next quad block (t += 1024)
        }
    }

    // ---- block-reduce the 13 scalars and finalize ----
    float vals[13] = {re[0], im[0], re[1], im[1], re[2], im[2], re[3], im[3],
                      re[4], im[4], E, sev + sod, sev - sod};
#pragma unroll
    for (int i = 0; i < 13; i++) {
        float v = wave_reduce_sum(vals[i]);
        if (lane == 0) rscratch[wid * 13 + i] = v;
    }
    __syncthreads();
    if (tid == 0) {
        float tot[13];
        for (int i = 0; i < 13; i++)
            tot[i] = rscratch[i] + rscratch[13 + i] + rscratch[26 + i] + rscratch[39 + i];
        float dsum = 0, isum = 0;
        for (int q = 0; q < TOPK; q++) {
            float rr = tot[2 * q], ii = tot[2 * q + 1];
            float dr = tgtF[q].x - rr, di = tgtF[q].y - ii;
            dsum += dr * dr + di * di;
            isum += rr * rr + ii * ii;
        }
        float Ee = tot[10], X0v = tot[11], Xhv = tot[12];
        float S_all = 0.5f * ((float)T_N * Ee + X0v * X0v + Xhv * Xhv);
        float val = sqrtf(dsum) + sqrtf(fmaxf(S_all - isum, 0.0f));
        atomicAdd(acc + 1, val);
    }
}

// ---------------- GEMM: sum |A (2048xK) . B^T (2048xK)| ----------------
// T4 counted-vmcnt pipeline: BK=64, 3-buffer LDS ring, stage issued 2 tiles
// ahead, steady-state s_waitcnt vmcnt(4) (never 0 in the loop). T2 swizzle:
// gload_lds dest stays LINEAR; the global SOURCE address is inverse-swizzled
// (rule #21 / m173) and ds_read applies byte ^= ((row&7)<<4) -> each
// quarter-wave's 16 lanes hit 8 distinct 16B slots (2-way residual = free).
// Stage issue sits AFTER the barrier: buf[(t+2)%3] == buf[(t-1)%3], whose
// reads completed before any wave entered the step-t barrier (MFMA data deps).
__global__ __launch_bounds__(512) void gemm_kernel(const ushort_t* __restrict__ A,
                                                   const ushort_t* __restrict__ Bm,
                                                   float* acc) {
    __shared__ __align__(16) ushort_t sA[3][128 * 64];
    __shared__ __align__(16) ushort_t sB[3][128 * 64];
    __shared__ float scratch[8];
    const int K = T_N;
    const int NSTEP = K / 64;  // 128
    int tid = threadIdx.x;

    // T1: bijective XCD swizzle for 256 blocks
    int bid = blockIdx.x;
    int swz = ((bid & 7) << 5) | (bid >> 3);
    int bx = swz >> 4, by = swz & 15;
    int row0 = bx * 128, col0 = by * 128;

    int w = tid >> 6, lane = tid & 63;
    int wm = w >> 2, wn = w & 3;  // 2x4 waves; per-wave output 64x32
    int lr = lane & 15, kq = lane >> 4;

    f32x4 accf[4][2];
#pragma unroll
    for (int mi = 0; mi < 4; mi++)
#pragma unroll
        for (int ni = 0; ni < 2; ni++) accf[mi][ni] = (f32x4){0.f, 0.f, 0.f, 0.f};

    // ---- staging addresses (inverse-swizzled global source, linear LDS dest)
    // LDS byte L = r*8192 + tid*16 -> row = r*64 + (tid>>3), slot = tid&7,
    // logical col-block cbl = slot ^ (row&7) = (tid&7) ^ ((tid>>3)&7).
    int strow = tid >> 3;                       // 0..63
    int scb = (tid & 7) ^ (strow & 7);          // logical 16B col-block 0..7
    const ushort_t* gA0 = A + (size_t)(row0 + strow) * K + scb * 8;
    const ushort_t* gA1 = A + (size_t)(row0 + 64 + strow) * K + scb * 8;
    const ushort_t* gB0 = Bm + (size_t)(col0 + strow) * K + scb * 8;
    const ushort_t* gB1 = Bm + (size_t)(col0 + 64 + strow) * K + scb * 8;
    int ldst0 = tid * 8;            // ushort index (tid*16 bytes)
    int ldst1 = 4096 + tid * 8;

    // ---- swizzled read offsets (ushort units): row*64 + ((cb ^ (row&7))<<3)
    int aoffs[2][4], boffs[2][2];
#pragma unroll
    for (int kk = 0; kk < 2; kk++) {
#pragma unroll
        for (int mi = 0; mi < 4; mi++) {
            int row = wm * 64 + mi * 16 + lr;
            aoffs[kk][mi] = row * 64 + (((kk * 4 + kq) ^ (lr & 7)) << 3);
        }
#pragma unroll
        for (int ni = 0; ni < 2; ni++) {
            int row = wn * 32 + ni * 16 + lr;
            boffs[kk][ni] = row * 64 + (((kk * 4 + kq) ^ (lr & 7)) << 3);
        }
    }

#define STAGE(bi, k0)                                  \
    do {                                               \
        gload_lds16(gA0 + (k0), &sA[bi][ldst0]);       \
        gload_lds16(gA1 + (k0), &sA[bi][ldst1]);       \
        gload_lds16(gB0 + (k0), &sB[bi][ldst0]);       \
        gload_lds16(gB1 + (k0), &sB[bi][ldst1]);       \
    } while (0)

    // prologue: stage tiles 0,1 (8 loads outstanding)
    STAGE(0, 0);
    STAGE(1, 64);

    for (int t = 0; t < NSTEP; ++t) {
        // wait until stage(t) landed: outstanding newest = stage(t+1) (4 loads)
        if (t + 1 < NSTEP)
            asm volatile("s_waitcnt vmcnt(4)" ::: "memory");
        else
            asm volatile("s_waitcnt vmcnt(0)" ::: "memory");
        __builtin_amdgcn_s_barrier();
        __builtin_amdgcn_sched_barrier(0);

        // issue stage(t+2) into buf[(t+2)%3] (== buf[(t-1)%3], reads done)
        if (t + 2 < NSTEP) {
            int bi = (t + 2) % 3;
            int k0 = (t + 2) * 64;
            STAGE(bi, k0);
        }

        // compute from buf[t%3]
        const ushort_t* As = sA[t % 3];
        const ushort_t* Bs = sB[t % 3];
        bf16x8 af0[4], bf0[2], af1[4], bf1[2];
#pragma unroll
        for (int mi = 0; mi < 4; mi++)
            af0[mi] = *reinterpret_cast<const bf16x8*>(As + aoffs[0][mi]);
#pragma unroll
        for (int ni = 0; ni < 2; ni++)
            bf0[ni] = *reinterpret_cast<const bf16x8*>(Bs + boffs[0][ni]);
#pragma unroll
        for (int mi = 0; mi < 4; mi++)
            af1[mi] = *reinterpret_cast<const bf16x8*>(As + aoffs[1][mi]);
#pragma unroll
        for (int ni = 0; ni < 2; ni++)
            bf1[ni] = *reinterpret_cast<const bf16x8*>(Bs + boffs[1][ni]);

        __builtin_amdgcn_s_setprio(1);
#pragma unroll
        for (int mi = 0; mi < 4; mi++)
#pragma unroll
            for (int ni = 0; ni < 2; ni++)
                accf[mi][ni] = __builtin_amdgcn_mfma_f32_16x16x32_bf16(
                    af0[mi], bf0[ni], accf[mi][ni], 0, 0, 0);
#pragma unroll
        for (int mi = 0; mi < 4; mi++)
#pragma unroll
            for (int ni = 0; ni < 2; ni++)
                accf[mi][ni] = __builtin_amdgcn_mfma_f32_16x16x32_bf16(
                    af1[mi], bf1[ni], accf[mi][ni], 0, 0, 0);
        __builtin_amdgcn_s_setprio(0);
    }
#undef STAGE

    // epilogue: in-register abs-sum, one atomic per block
    float s = 0.0f;
#pragma unroll
    for (int mi = 0; mi < 4; mi++)
#pragma unroll
        for (int ni = 0; ni < 2; ni++)
#pragma unroll
            for (int r = 0; r < 4; r++) s += fabsf(accf[mi][ni][r]);
    s = wave_reduce_sum(s);
    if (lane == 0) scratch[w] = s;
    __syncthreads();
    if (tid == 0) {
        float tot = 0.0f;
        for (int i = 0; i < 8; i++) tot += scratch[i];
        atomicAdd(acc, tot);
    }
}

// ---------------- combine ----------------
__global__ void combine_kernel(const float* acc, float* out) {
    if (threadIdx.x == 0) {
        float ash = acc[0] / (float)B_N;
        float ph = acc[1] / (float)B_N;
        float am = acc[2] / ((float)B_N * (float)B_N);
        out[0] = 0.5f * ash + 0.5f * ph + 0.01f * am;
    }
}

extern "C" void kernel_launch(void* const* d_in, const int* in_sizes, int n_in,
                              void* d_out, int out_size, void* d_ws, size_t ws_size,
                              hipStream_t stream) {
    const float* inp = (const float*)d_in[0];
    const float* tgt = (const float*)d_in[1];
    float* acc = (float*)d_ws;
    ushort_t* Abf = (ushort_t*)((char*)d_ws + 256);
    ushort_t* Bbf = Abf + (size_t)B_N * T_N;
    float* out = (float*)d_out;

    hipLaunchKernelGGL(init_kernel, dim3(1), dim3(64), 0, stream, acc);
    hipLaunchKernelGGL(fused_row_kernel, dim3(B_N), dim3(256), 0, stream,
                       inp, tgt, Abf, Bbf, acc);
    hipLaunchKernelGGL(gemm_kernel, dim3(256), dim3(512), 0, stream, Abf, Bbf, acc + 2);
    hipLaunchKernelGGL(combine_kernel, dim3(1), dim3(1), 0, stream, acc, out);
}

// Round 4
// 184.020 us; speedup vs baseline: 1.1000x; 1.1000x over previous
//
#include <hip/hip_runtime.h>
#include <hip/hip_bf16.h>
#include <math.h>

#define B_N 2048
#define T_N 8192
#define NFFT 4096
#define TF_LEN 4097
#define TOPK 5
#define KSPLIT 4
#define GBK 64

// padded LDS index for float2 Zs array: breaks power-of-2 stride bank conflicts
#define ZIDX(n) ((n) + ((n) >> 4))
#define ZPAD (NFFT + (NFFT >> 4))  // 4352 float2 slots

typedef float f32x4 __attribute__((ext_vector_type(4)));
typedef __bf16 bf16x8 __attribute__((ext_vector_type(8)));
typedef unsigned short ushort_t;

__device__ __forceinline__ void gload_lds16(const ushort_t* g, ushort_t* l) {
    __builtin_amdgcn_global_load_lds(
        (const __attribute__((address_space(1))) void*)g,
        (__attribute__((address_space(3))) void*)l,
        16, 0, 0);
}

__device__ __forceinline__ float wave_reduce_sum(float v) {
    for (int o = 32; o >= 1; o >>= 1) v += __shfl_xor(v, o, 64);
    return v;
}
__device__ __forceinline__ float wave_reduce_max(float v) {
    for (int o = 32; o >= 1; o >>= 1) v = fmaxf(v, __shfl_xor(v, o, 64));
    return v;
}

__device__ __forceinline__ ushort_t f2bf(float x) {
    __hip_bfloat16 h = __float2bfloat16(x);
    return *reinterpret_cast<ushort_t*>(&h);
}

// native HW trig: input in REVOLUTIONS; cis_rev(r) = (cos(2*pi*r), sin(2*pi*r))
__device__ __forceinline__ float2 cis_rev(float rev) {
    return make_float2(__builtin_amdgcn_cosf(rev), __builtin_amdgcn_sinf(rev));
}
__device__ __forceinline__ float2 cmulf(float2 a, float2 b) {
    return make_float2(a.x * b.x - a.y * b.y, a.x * b.y + a.y * b.x);
}

// ---------------- init: zero acc (+ Cpart when atomic fallback) ----------------
__global__ __launch_bounds__(256) void init_kernel(float* acc, float* Cpart, int nzbuf) {
    if (blockIdx.x == 0 && threadIdx.x < 4) acc[threadIdx.x] = 0.0f;
    if (nzbuf == 1) {
        size_t idx = ((size_t)blockIdx.x * 256 + threadIdx.x) * 4;
        *reinterpret_cast<f32x4*>(&Cpart[idx]) = (f32x4){0.f, 0.f, 0.f, 0.f};
    }
}

// ---------------- DFT16 in registers (two radix-4 levels) ----------------
__device__ __forceinline__ void dft4(float2 x0, float2 x1, float2 x2, float2 x3,
                                     float2* y0, float2* y1, float2* y2, float2* y3) {
    float2 t0 = make_float2(x0.x + x2.x, x0.y + x2.y);
    float2 t1 = make_float2(x0.x - x2.x, x0.y - x2.y);
    float2 t2 = make_float2(x1.x + x3.x, x1.y + x3.y);
    float2 t3 = make_float2(x1.x - x3.x, x1.y - x3.y);
    *y0 = make_float2(t0.x + t2.x, t0.y + t2.y);
    *y2 = make_float2(t0.x - t2.x, t0.y - t2.y);
    *y1 = make_float2(t1.x + t3.y, t1.y - t3.x);   // t1 + (-i)*t3
    *y3 = make_float2(t1.x - t3.y, t1.y + t3.x);   // t1 - (-i)*t3
}

__device__ __forceinline__ void dft16(float2 X[16]) {
    float2 G[16];
    // G[b*4+c] = DFT4 over a of X[4a+b]
    dft4(X[0], X[4], X[8],  X[12], &G[0],  &G[1],  &G[2],  &G[3]);
    dft4(X[1], X[5], X[9],  X[13], &G[4],  &G[5],  &G[6],  &G[7]);
    dft4(X[2], X[6], X[10], X[14], &G[8],  &G[9],  &G[10], &G[11]);
    dft4(X[3], X[7], X[11], X[15], &G[12], &G[13], &G[14], &G[15]);
    const float C1 = 0.9238795325112867f, S1 = 0.3826834323650898f;
    const float R2 = 0.7071067811865476f;
    // H[b][c] = G[b][c] * W16^{bc}
    G[5]  = cmulf(G[5],  make_float2(C1, -S1));   // W^1
    G[6]  = cmulf(G[6],  make_float2(R2, -R2));   // W^2
    G[7]  = cmulf(G[7],  make_float2(S1, -C1));   // W^3
    G[9]  = cmulf(G[9],  make_float2(R2, -R2));   // W^2
    { float2 g = G[10]; G[10] = make_float2(g.y, -g.x); }  // W^4 = -i
    G[11] = cmulf(G[11], make_float2(-R2, -R2));  // W^6
    G[13] = cmulf(G[13], make_float2(S1, -C1));   // W^3
    G[14] = cmulf(G[14], make_float2(-R2, -R2));  // W^6
    G[15] = cmulf(G[15], make_float2(-C1, S1));   // W^9
    // Y[c+4d] = DFT4 over b of H[b][c]
    dft4(G[0], G[4], G[8],  G[12], &X[0], &X[4], &X[8],  &X[12]);
    dft4(G[1], G[5], G[9],  G[13], &X[1], &X[5], &X[9],  &X[13]);
    dft4(G[2], G[6], G[10], G[14], &X[2], &X[6], &X[10], &X[14]);
    dft4(G[3], G[7], G[11], G[15], &X[3], &X[7], &X[11], &X[15]);
}

// rfft bin from packed-complex spectrum (exact path, used for top bins)
__device__ __forceinline__ void rfft_bin(const float2* Zs, int k, float* orr, float* oi) {
    int kk = k & (NFFT - 1);
    int nk = (NFFT - k) & (NFFT - 1);
    float2 zk = Zs[ZIDX(kk)], znk = Zs[ZIDX(nk)];
    float xer = 0.5f * (zk.x + znk.x);
    float xei = 0.5f * (zk.y - znk.y);
    float xo_r = 0.5f * (zk.y + znk.y);
    float xo_i = -0.5f * (zk.x - znk.x);
    float2 w = cis_rev((float)k * (-1.0f / (float)T_N));
    *orr = xer + w.x * xo_r - w.y * xo_i;
    *oi = xei + w.x * xo_i + w.y * xo_r;
}

// ---------------- fused per-row kernel: prep + ashift + phase ----------------
__global__ __launch_bounds__(256) void fused_row_kernel(const float* __restrict__ inp,
                                                        const float* __restrict__ tgt,
                                                        ushort_t* __restrict__ Abf,
                                                        ushort_t* __restrict__ Bbf,
                                                        float* acc) {
    __shared__ float2 Zs[ZPAD];
    __shared__ __align__(16) float amp[TF_LEN];
    __shared__ float red[4];
    __shared__ float wv[4];
    __shared__ int wi[4];
    __shared__ int topIdx[TOPK];
    __shared__ float2 tgtF[TOPK];
    __shared__ float rscratch[64];

    int b = blockIdx.x;
    int tid = threadIdx.x;
    int lane = tid & 63, wid = tid >> 6;
    const float* tp = tgt + (size_t)b * T_N;
    const float* ip = inp + (size_t)b * T_N;
    ushort_t* Ab = Abf + (size_t)b * T_N;
    ushort_t* Bb = Bbf + (size_t)b * T_N;

    // ---- load tgt: regs + Abf + digit-reversed complex scatter into Zs ----
    float4 trv[8];
#pragma unroll
    for (int i = 0; i < 8; i++) {
        int q = tid + 256 * i;
        trv[i] = *reinterpret_cast<const float4*>(&tp[4 * q]);
        ushort4 ua;
        ua.x = f2bf(trv[i].x); ua.y = f2bf(trv[i].y);
        ua.z = f2bf(trv[i].z); ua.w = f2bf(trv[i].w);
        *reinterpret_cast<ushort4*>(&Ab[4 * q]) = ua;
        int m0 = 2 * q, m1 = 2 * q + 1;
        int p0 = ((m0 & 15) << 8) | (m0 & 0x0F0) | (m0 >> 8);
        int p1 = ((m1 & 15) << 8) | (m1 & 0x0F0) | (m1 >> 8);
        Zs[ZIDX(p0)] = make_float2(trv[i].x, trv[i].y);
        Zs[ZIDX(p1)] = make_float2(trv[i].z, trv[i].w);
    }

    // ---- load inp; d = inp - tgt (tgt regs die here) ----
    float4 irv[8], dv[8];
#pragma unroll
    for (int i = 0; i < 8; i++) {
        int q = tid + 256 * i;
        irv[i] = *reinterpret_cast<const float4*>(&ip[4 * q]);
        dv[i] = make_float4(irv[i].x - trv[i].x, irv[i].y - trv[i].y,
                            irv[i].z - trv[i].z, irv[i].w - trv[i].w);
    }

    // ---- Bbf = bf16(-d reversed), via two 16KB pings through amp[] ----
    float* ampf = amp;
#pragma unroll
    for (int i = 0; i < 4; i++)  // d[0..4095] -> ampf quads [0,1024)
        *reinterpret_cast<float4*>(&ampf[4 * (tid + 256 * i)]) = dv[i];
    __syncthreads();
#pragma unroll
    for (int i2 = 0; i2 < 4; i2++) {  // Bbf quads [1024,2048)
        int qr = 1024 + tid + 256 * i2;
        float4 v = *reinterpret_cast<const float4*>(&ampf[4 * (1023 - tid - 256 * i2)]);
        ushort4 ub;
        ub.x = f2bf(-v.w); ub.y = f2bf(-v.z); ub.z = f2bf(-v.y); ub.w = f2bf(-v.x);
        *reinterpret_cast<ushort4*>(&Bb[4 * qr]) = ub;
    }
    __syncthreads();
#pragma unroll
    for (int i = 4; i < 8; i++)  // d[4096..8191] -> ampf quads [0,1024)
        *reinterpret_cast<float4*>(&ampf[4 * (tid + 256 * (i - 4))]) = dv[i];
    __syncthreads();
#pragma unroll
    for (int i2 = 0; i2 < 4; i2++) {  // Bbf quads [0,1024)
        int qr = tid + 256 * i2;
        float4 v = *reinterpret_cast<const float4*>(&ampf[4 * (1023 - tid - 256 * i2)]);
        ushort4 ub;
        ub.x = f2bf(-v.w); ub.y = f2bf(-v.z); ub.z = f2bf(-v.y); ub.w = f2bf(-v.x);
        *reinterpret_cast<ushort4*>(&Bb[4 * qr]) = ub;
    }
    __syncthreads();

    // ---- ashift from d registers ----
    {
        float lmax = -1e30f;
#pragma unroll
        for (int i = 0; i < 8; i++)
            lmax = fmaxf(lmax, fmaxf(fmaxf(dv[i].x, dv[i].y), fmaxf(dv[i].z, dv[i].w)));
        lmax = wave_reduce_max(lmax);
        if (lane == 0) red[wid] = lmax;
        __syncthreads();
        float mx = fmaxf(fmaxf(red[0], red[1]), fmaxf(red[2], red[3]));
        __syncthreads();
        float lsum = 0.0f;
#pragma unroll
        for (int i = 0; i < 8; i++) {
            dv[i].x = __expf(dv[i].x - mx);
            dv[i].y = __expf(dv[i].y - mx);
            dv[i].z = __expf(dv[i].z - mx);
            dv[i].w = __expf(dv[i].w - mx);
            lsum += (dv[i].x + dv[i].y) + (dv[i].z + dv[i].w);
        }
        lsum = wave_reduce_sum(lsum);
        if (lane == 0) red[wid] = lsum;
        __syncthreads();
        float Z = (red[0] + red[1]) + (red[2] + red[3]);
        __syncthreads();
        float inv = 1.0f / Z;
        const float u = 1.0f / (float)T_N;
        float labs = 0.0f;
#pragma unroll
        for (int i = 0; i < 8; i++) {
            labs += fabsf(u - dv[i].x * inv) + fabsf(u - dv[i].y * inv) +
                    fabsf(u - dv[i].z * inv) + fabsf(u - dv[i].w * inv);
        }
        labs = wave_reduce_sum(labs);
        if (lane == 0) red[wid] = labs;
        __syncthreads();
        if (tid == 0)
            atomicAdd(acc + 0, (red[0] + red[1]) + (red[2] + red[3]));
    }
    __syncthreads();

    // ---- FFT: 3 radix-16 passes, in place (digit-reversed input) ----
    {  // pass 0: base 16t, stride 1, no twiddle
        float2 X[16];
        int base = tid * 16;
#pragma unroll
        for (int r = 0; r < 16; r++) X[r] = Zs[ZIDX(base + r)];
        dft16(X);
#pragma unroll
        for (int r = 0; r < 16; r++) Zs[ZIDX(base + r)] = X[r];
    }
    __syncthreads();
    {  // pass 1: base = (t>>4)*256 + (t&15), stride 16, twiddle W_256^{j r}
        float2 X[16];
        int j = tid & 15;
        int base = (tid >> 4) * 256 + j;
#pragma unroll
        for (int r = 0; r < 16; r++) X[r] = Zs[ZIDX(base + 16 * r)];
        float2 w1 = cis_rev(-(float)j * (1.0f / 256.0f));
        float2 w = w1;
#pragma unroll
        for (int r = 1; r < 16; r++) { X[r] = cmulf(X[r], w); w = cmulf(w, w1); }
        dft16(X);
#pragma unroll
        for (int r = 0; r < 16; r++) Zs[ZIDX(base + 16 * r)] = X[r];
    }
    __syncthreads();
    {  // pass 2: base = t, stride 256, twiddle W_4096^{t r}
        float2 X[16];
#pragma unroll
        for (int r = 0; r < 16; r++) X[r] = Zs[ZIDX(tid + 256 * r)];
        float2 w1 = cis_rev(-(float)tid * (1.0f / 4096.0f));
        float2 w = w1;
#pragma unroll
        for (int r = 1; r < 16; r++) { X[r] = cmulf(X[r], w); w = cmulf(w, w1); }
        dft16(X);
#pragma unroll
        for (int r = 0; r < 16; r++) Zs[ZIDX(tid + 256 * r)] = X[r];
    }
    __syncthreads();

    // ---- amplitude^2 of rfft bins (rotation recurrence, no sqrt) ----
    {
        float2 rot = cis_rev(-(float)tid * (1.0f / (float)T_N));
        const float2 drot = make_float2(0.9807852804032304f, -0.19509032201612825f);
#pragma unroll
        for (int i = 0; i < 16; i++) {
            int k = tid + 256 * i;
            if (k == 0) {
                amp[0] = -1.0f;
            } else {
                int nk = (NFFT - k) & (NFFT - 1);
                float2 zk = Zs[ZIDX(k & (NFFT - 1))], znk = Zs[ZIDX(nk)];
                float xer = 0.5f * (zk.x + znk.x);
                float xei = 0.5f * (zk.y - znk.y);
                float xo_r = 0.5f * (zk.y + znk.y);
                float xo_i = -0.5f * (zk.x - znk.x);
                float xr = xer + rot.x * xo_r - rot.y * xo_i;
                float xi = xei + rot.x * xo_i + rot.y * xo_r;
                amp[k] = xr * xr + xi * xi;
            }
            rot = cmulf(rot, drot);
        }
        if (tid == 0) {  // Nyquist bin 4096
            float2 z0 = Zs[ZIDX(0)];
            float v = z0.x - z0.y;
            amp[4096] = v * v;
        }
    }
    __syncthreads();

    // ---- top-5 by 5 sequential argmax rounds (tie -> smaller index) ----
    for (int r = 0; r < TOPK; r++) {
        float bv = -3.0f;
        int bi = TF_LEN;
        for (int k = tid; k < TF_LEN; k += 256) {
            float a = amp[k];
            if (a > bv) { bv = a; bi = k; }
        }
        for (int o = 1; o < 64; o <<= 1) {
            float ov = __shfl_xor(bv, o, 64);
            int oi = __shfl_xor(bi, o, 64);
            if (ov > bv || (ov == bv && oi < bi)) { bv = ov; bi = oi; }
        }
        if (lane == 0) { wv[wid] = bv; wi[wid] = bi; }
        __syncthreads();
        if (tid == 0) {
            float fv = wv[0];
            int fi = wi[0];
            for (int w = 1; w < 4; w++)
                if (wv[w] > fv || (wv[w] == fv && wi[w] < fi)) { fv = wv[w]; fi = wi[w]; }
            topIdx[r] = fi;
            amp[fi] = -2.0f;
        }
        __syncthreads();
    }

    // ---- exact target spectrum at top bins ----
    if (tid < TOPK) {
        float xr, xi;
        rfft_bin(Zs, topIdx[tid], &xr, &xi);
        tgtF[tid] = make_float2(xr, xi);
    }
    __syncthreads();

    int fq[TOPK];
#pragma unroll
    for (int q = 0; q < TOPK; q++) fq[q] = topIdx[q];

    // ---- direct DFT of input (from registers) at 5 bins + energy terms ----
    float2 cur[TOPK], wc[TOPK], wf[TOPK];
    float re[TOPK], im[TOPK];
#pragma unroll
    for (int q = 0; q < TOPK; q++) {
        int f = fq[q];
        cur[q] = cis_rev(-(float)((f * 4 * tid) & (T_N - 1)) * (1.0f / (float)T_N));
        wc[q] = cis_rev(-(float)f * (1.0f / (float)T_N));
        wf[q] = cis_rev(-(float)((f * 1021) & (T_N - 1)) * (1.0f / (float)T_N));
        re[q] = 0.0f; im[q] = 0.0f;
    }
    float E = 0.0f, sev = 0.0f, sod = 0.0f;
#pragma unroll
    for (int i = 0; i < 8; i++) {
        float vv0 = irv[i].x, vv1 = irv[i].y, vv2 = irv[i].z, vv3 = irv[i].w;
        E = fmaf(vv0, vv0, E); sev += vv0;
#pragma unroll
        for (int q = 0; q < TOPK; q++) {
            re[q] = fmaf(vv0, cur[q].x, re[q]); im[q] = fmaf(vv0, cur[q].y, im[q]);
            cur[q] = cmulf(cur[q], wc[q]);
        }
        E = fmaf(vv1, vv1, E); sod += vv1;
#pragma unroll
        for (int q = 0; q < TOPK; q++) {
            re[q] = fmaf(vv1, cur[q].x, re[q]); im[q] = fmaf(vv1, cur[q].y, im[q]);
            cur[q] = cmulf(cur[q], wc[q]);
        }
        E = fmaf(vv2, vv2, E); sev += vv2;
#pragma unroll
        for (int q = 0; q < TOPK; q++) {
            re[q] = fmaf(vv2, cur[q].x, re[q]); im[q] = fmaf(vv2, cur[q].y, im[q]);
            cur[q] = cmulf(cur[q], wc[q]);
        }
        E = fmaf(vv3, vv3, E); sod += vv3;
#pragma unroll
        for (int q = 0; q < TOPK; q++) {
            re[q] = fmaf(vv3, cur[q].x, re[q]); im[q] = fmaf(vv3, cur[q].y, im[q]);
            cur[q] = cmulf(cur[q], wf[q]);  // jump to next quad block (t += 1024)
        }
    }

    // ---- block-reduce the 13 scalars and finalize ----
    float vals[13] = {re[0], im[0], re[1], im[1], re[2], im[2], re[3], im[3],
                      re[4], im[4], E, sev + sod, sev - sod};
#pragma unroll
    for (int i = 0; i < 13; i++) {
        float v = wave_reduce_sum(vals[i]);
        if (lane == 0) rscratch[wid * 13 + i] = v;
    }
    __syncthreads();
    if (tid == 0) {
        float tot[13];
        for (int i = 0; i < 13; i++)
            tot[i] = rscratch[i] + rscratch[13 + i] + rscratch[26 + i] + rscratch[39 + i];
        float dsum = 0, isum = 0;
        for (int q = 0; q < TOPK; q++) {
            float rr = tot[2 * q], ii = tot[2 * q + 1];
            float dr = tgtF[q].x - rr, di = tgtF[q].y - ii;
            dsum += dr * dr + di * di;
            isum += rr * rr + ii * ii;
        }
        float Ee = tot[10], X0v = tot[11], Xhv = tot[12];
        float S_all = 0.5f * ((float)T_N * Ee + X0v * X0v + Xhv * Xhv);
        float val = sqrtf(dsum) + sqrtf(fmaxf(S_all - isum, 0.0f));
        atomicAdd(acc + 1, val);
    }
}

// ---------------- GEMM: 256x256 tile, 8-phase counted-vmcnt schedule ----------------
// m201 template port. 8 waves 2Mx4N, per-wave 128x64 out. LDS 128KB:
// lds[buf 0/1][region A0,A1,B0,B1][128x64 bf16]. Per phase: 12 ds_read_b128 +
// 2 gload_lds (one region-pair) + barrier + setprio{16 MFMA} + barrier.
// Quadrant order per tile: (qm,qn) = (0,0),(0,1),(1,0),(1,1) so A.s0 frees
// after ph2. Staging slots (iter i, phases 1-8):
//   ph1:(2i+1).B1  ph2:(2i+1).B0  ph3:(2i+2).A.s0  ph4:(2i+1).A.s1
//   ph5:(2i+2).B1  ph6:(2i+2).B0  ph7:(2i+2).A.s1  ph8:(2i+3).A.s0
// vmcnt ledger (2 loads/phase continuous; gate at phase q forces phases
// <= q-1-N/2; cross-wave needs gate_{p-1} to force phase p's min-lead):
// per-phase N = [4,4,6,2,4,2,4,2] -- counted, NEVER 0 in the loop (T4).
// Tail: restage same-parity current tiles (identical bytes) to keep the
// issue stream exactly 2/phase so the ledger stays valid.
// T2 swizzle: linear gload dest + inverse-swizzled global source + XOR read.
// KSPLIT=4 for occupancy (64 tiles -> 256 blocks): partials stored plain
// (nzbuf==4) or atomicAdd fallback (nzbuf==1) if workspace is small.
__global__ __launch_bounds__(512, 2) void gemm_kernel(const ushort_t* __restrict__ A,
                                                      const ushort_t* __restrict__ Bm,
                                                      float* __restrict__ Cpart,
                                                      int nzbuf) {
    __shared__ __align__(16) ushort_t lds[2][4][128 * 64];
    int tid = threadIdx.x;
    int bid = blockIdx.x;
    int swz = ((bid & 7) << 5) | (bid >> 3);   // bijective on [0,256): XCD = bid&7
    int bx = swz & 7, by = (swz >> 3) & 7, bz = swz >> 6;
    int row0 = bx * 256, col0 = by * 256;
    const int KC = T_N / KSPLIT;   // 2048
    const int NT = KC / GBK;       // 32
    const int NIT = NT / 2;        // 16
    int kbase = bz * KC;

    int w = tid >> 6, lane = tid & 63;
    int wm = w >> 2, wn = w & 3;   // 2M x 4N waves
    int lr = lane & 15, kq = lane >> 4;

    f32x4 accf[8][4];
#pragma unroll
    for (int mi = 0; mi < 8; mi++)
#pragma unroll
        for (int ni = 0; ni < 4; ni++) accf[mi][ni] = (f32x4){0.f, 0.f, 0.f, 0.f};

    // staging: thread -> (row-in-subhalf, inverse-swizzled col-block)
    int strow = tid >> 3;                 // 0..63
    int scb = (tid & 7) ^ (strow & 7);    // logical 16B col-block
    const ushort_t* gA0 = A + (size_t)(row0 + strow) * T_N + kbase + scb * 8;
    const ushort_t* gA1 = A + (size_t)(row0 + 128 + strow) * T_N + kbase + scb * 8;
    const ushort_t* gB0 = Bm + (size_t)(col0 + strow) * T_N + kbase + scb * 8;
    const ushort_t* gB1 = Bm + (size_t)(col0 + 128 + strow) * T_N + kbase + scb * 8;
    const size_t SUB = (size_t)64 * T_N;  // +64 rows

    // swizzled ds_read bases (ushort units): row*64 + ((cb ^ (row&7))<<3)
    int rb0 = lr * 64 + ((kq ^ (lr & 7)) << 3);        // k-slice 0 (cb = kq)
    int rb1 = lr * 64 + (((4 + kq) ^ (lr & 7)) << 3);  // k-slice 1 (cb = 4+kq)

#define SA_(s, buf, kt)                                                        \
    do {                                                                       \
        gload_lds16(gA0 + (s) * SUB + (size_t)(kt) * GBK, &lds[buf][0][(s) * 4096 + tid * 8]); \
        gload_lds16(gA1 + (s) * SUB + (size_t)(kt) * GBK, &lds[buf][1][(s) * 4096 + tid * 8]); \
    } while (0)
#define SB_(rg, buf, kt)                                                       \
    do {                                                                       \
        const ushort_t* g_ = ((rg) == 2) ? gB0 : gB1;                          \
        gload_lds16(g_ + (size_t)(kt) * GBK, &lds[buf][rg][tid * 8]);          \
        gload_lds16(g_ + SUB + (size_t)(kt) * GBK, &lds[buf][rg][4096 + tid * 8]); \
    } while (0)

#define PHASE(BUF, QM, QN, VMN, STAGE_STMT)                                    \
    do {                                                                       \
        asm volatile("s_waitcnt vmcnt(" #VMN ")" ::: "memory");                \
        const ushort_t* Ab_ = &lds[BUF][wm][0];                                \
        const ushort_t* Bb_ = &lds[BUF][2 + (wn >> 1)][(wn & 1) * 4096];       \
        bf16x8 a_[4][2], b_[2][2];                                             \
        _Pragma("unroll") for (int m_ = 0; m_ < 4; m_++) {                     \
            a_[m_][0] = *reinterpret_cast<const bf16x8*>(Ab_ + (QM) * 4096 + m_ * 1024 + rb0); \
            a_[m_][1] = *reinterpret_cast<const bf16x8*>(Ab_ + (QM) * 4096 + m_ * 1024 + rb1); \
        }                                                                      \
        _Pragma("unroll") for (int n_ = 0; n_ < 2; n_++) {                     \
            b_[n_][0] = *reinterpret_cast<const bf16x8*>(Bb_ + (QN) * 2048 + n_ * 1024 + rb0); \
            b_[n_][1] = *reinterpret_cast<const bf16x8*>(Bb_ + (QN) * 2048 + n_ * 1024 + rb1); \
        }                                                                      \
        STAGE_STMT;                                                            \
        __builtin_amdgcn_s_barrier();                                          \
        __builtin_amdgcn_s_setprio(1);                                         \
        _Pragma("unroll") for (int m_ = 0; m_ < 4; m_++)                       \
        _Pragma("unroll") for (int n_ = 0; n_ < 2; n_++) {                     \
            accf[(QM) * 4 + m_][(QN) * 2 + n_] = __builtin_amdgcn_mfma_f32_16x16x32_bf16( \
                a_[m_][0], b_[n_][0], accf[(QM) * 4 + m_][(QN) * 2 + n_], 0, 0, 0); \
            accf[(QM) * 4 + m_][(QN) * 2 + n_] = __builtin_amdgcn_mfma_f32_16x16x32_bf16( \
                a_[m_][1], b_[n_][1], accf[(QM) * 4 + m_][(QN) * 2 + n_], 0, 0, 0); \
        }                                                                      \
        __builtin_amdgcn_s_setprio(0);                                         \
        __builtin_amdgcn_s_barrier();                                          \
    } while (0)

    // prologue: tile0 fully (A.s0, A.s1, B0, B1) + tile1.A.s0; drain to 2.
    SA_(0, 0, 0);
    SA_(1, 0, 0);
    SB_(2, 0, 0);
    SB_(3, 0, 0);
    SA_(0, 1, 1);
    asm volatile("s_waitcnt vmcnt(2)" ::: "memory");
    __builtin_amdgcn_s_barrier();

    for (int it = 0; it < NIT; ++it) {
        int kt1 = 2 * it + 1;
        int te = (2 * it + 2 < NT) ? 2 * it + 2 : 2 * it;  // even tile (buf0)
        int to = (kt1 + 2 < NT) ? kt1 + 2 : kt1;           // odd tile (buf1)
        PHASE(0, 0, 0, 4, SB_(3, 1, kt1));
        PHASE(0, 0, 1, 4, SB_(2, 1, kt1));
        PHASE(0, 1, 0, 6, SA_(0, 0, te));
        PHASE(0, 1, 1, 2, SA_(1, 1, kt1));
        PHASE(1, 0, 0, 4, SB_(3, 0, te));
        PHASE(1, 0, 1, 2, SB_(2, 0, te));
        PHASE(1, 1, 0, 4, SA_(1, 0, te));
        PHASE(1, 1, 1, 2, SA_(0, 1, to));
    }
#undef PHASE
#undef SA_
#undef SB_

    // epilogue: store partial tile (plain stores; atomic fallback if nzbuf==1)
    int crow = row0 + wm * 128 + (lane >> 4) * 4;
    int ccol = col0 + wn * 64 + lr;
    if (nzbuf == 4) {
        float* Cp = Cpart + (size_t)bz * ((size_t)B_N * B_N);
#pragma unroll
        for (int mi = 0; mi < 8; mi++)
#pragma unroll
            for (int ni = 0; ni < 4; ni++)
#pragma unroll
                for (int r = 0; r < 4; r++)
                    Cp[(size_t)(crow + mi * 16 + r) * B_N + ccol + ni * 16] =
                        accf[mi][ni][r];
    } else {
#pragma unroll
        for (int mi = 0; mi < 8; mi++)
#pragma unroll
            for (int ni = 0; ni < 4; ni++)
#pragma unroll
                for (int r = 0; r < 4; r++)
                    atomicAdd(&Cpart[(size_t)(crow + mi * 16 + r) * B_N + ccol + ni * 16],
                              accf[mi][ni][r]);
    }
}

// ---------------- abs-reduce of summed partials into acc[2] ----------------
__global__ __launch_bounds__(256) void absum_kernel(const float* __restrict__ C,
                                                    float* acc, int nzbuf) {
    __shared__ float sred[4];
    int tid = threadIdx.x;
    int lane = tid & 63, wid = tid >> 6;
    const size_t NN = (size_t)B_N * B_N;
    size_t base = (size_t)blockIdx.x * 4096;  // 1024 blocks x 4096 floats
    float s = 0.0f;
#pragma unroll
    for (int i = 0; i < 4; i++) {
        size_t idx = base + (size_t)(tid + 256 * i) * 4;
        f32x4 v = *reinterpret_cast<const f32x4*>(&C[idx]);
        if (nzbuf == 4) {
            v += *reinterpret_cast<const f32x4*>(&C[NN + idx]);
            v += *reinterpret_cast<const f32x4*>(&C[2 * NN + idx]);
            v += *reinterpret_cast<const f32x4*>(&C[3 * NN + idx]);
        }
        s += fabsf(v.x) + fabsf(v.y) + fabsf(v.z) + fabsf(v.w);
    }
    s = wave_reduce_sum(s);
    if (lane == 0) sred[wid] = s;
    __syncthreads();
    if (tid == 0) atomicAdd(acc + 2, sred[0] + sred[1] + sred[2] + sred[3]);
}

// ---------------- combine ----------------
__global__ void combine_kernel(const float* acc, float* out) {
    if (threadIdx.x == 0) {
        float ash = acc[0] / (float)B_N;
        float ph = acc[1] / (float)B_N;
        float am = acc[2] / ((float)B_N * (float)B_N);
        out[0] = 0.5f * ash + 0.5f * ph + 0.01f * am;
    }
}

extern "C" void kernel_launch(void* const* d_in, const int* in_sizes, int n_in,
                              void* d_out, int out_size, void* d_ws, size_t ws_size,
                              hipStream_t stream) {
    const float* inp = (const float*)d_in[0];
    const float* tgt = (const float*)d_in[1];
    float* acc = (float*)d_ws;
    ushort_t* Abf = (ushort_t*)((char*)d_ws + 256);
    ushort_t* Bbf = Abf + (size_t)B_N * T_N;
    float* Cpart = (float*)(Bbf + (size_t)B_N * T_N);
    float* out = (float*)d_out;

    size_t need4 = 256 + 2 * (size_t)B_N * T_N * sizeof(ushort_t)
                 + (size_t)KSPLIT * (size_t)B_N * B_N * sizeof(float);
    int nzbuf = (ws_size >= need4) ? 4 : 1;

    hipLaunchKernelGGL(init_kernel, dim3(nzbuf == 1 ? 4096 : 1), dim3(256), 0, stream,
                       acc, Cpart, nzbuf);
    hipLaunchKernelGGL(fused_row_kernel, dim3(B_N), dim3(256), 0, stream,
                       inp, tgt, Abf, Bbf, acc);
    hipLaunchKernelGGL(gemm_kernel, dim3(256), dim3(512), 0, stream,
                       Abf, Bbf, Cpart, nzbuf);
    hipLaunchKernelGGL(absum_kernel, dim3(1024), dim3(256), 0, stream,
                       Cpart, acc, nzbuf);
    hipLaunchKernelGGL(combine_kernel, dim3(1), dim3(1), 0, stream, acc, out);
}